// Round 1
// baseline (59.065 us; speedup 1.0000x reference)
//
#include <hip/hip_runtime.h>
#include <math.h>

#define B_  16
#define T_  16
#define N_  256
#define D_  384
#define Q_  384
#define K_  16
#define BT_ (B_ * T_)
#define NTHREADS 512

// One block per (b,t). Phases:
//  1. q_proj = queries[bt] @ W_in + b_in              (D_ outputs)
//  2. scores[n] = dot(q_proj, patch[bt,n,:])          (N_ outputs)
//  3. softmax + exact top-K selection via rank count
//  4. out_d = sum_{j<K} w_j * patch[bt, idx_j, :]     (only K rows)
//  5. out = out_d @ W_out + b_out                     (Q_ outputs)
__global__ __launch_bounds__(NTHREADS)
void attn_topk_kernel(const float* __restrict__ queries,   // [BT_, Q_]
                      const float* __restrict__ patch,     // [BT_, N_, D_]
                      const float* __restrict__ W_in,      // [Q_, D_]
                      const float* __restrict__ b_in,      // [D_]
                      const float* __restrict__ W_out,     // [D_, Q_]
                      const float* __restrict__ b_out,     // [Q_]
                      float* __restrict__ out)             // [BT_, Q_]
{
    const int bt   = blockIdx.x;       // 0..255
    const int tid  = threadIdx.x;      // 0..511
    const int lane = tid & 63;
    const int wave = tid >> 6;         // 0..7

    __shared__ float s_q[Q_];          // query row
    __shared__ float s_qp[D_];         // projected query
    __shared__ float s_sc[N_];         // scores
    __shared__ float s_red[8];         // wave max
    __shared__ float s_red2[8][2];     // wave {Z, S_k}
    __shared__ float s_w[K_];          // top-k weights (renormalized)
    __shared__ int   s_ix[K_];         // top-k indices
    __shared__ float s_od[D_];         // weighted-sum output (pre out-proj)

    const float* __restrict__ qrow  = queries + (size_t)bt * Q_;
    const float* __restrict__ ptile = patch   + (size_t)bt * N_ * D_;

    if (tid < Q_) s_q[tid] = qrow[tid];
    __syncthreads();

    // ---- 1. q_proj ----
    if (tid < D_) {
        float acc = b_in[tid];
        #pragma unroll 8
        for (int q = 0; q < Q_; ++q)
            acc += s_q[q] * W_in[(size_t)q * D_ + tid];
        s_qp[tid] = acc;
    }
    __syncthreads();

    // ---- 2. scores ----  (16-lane groups, 4 rows per wave-iteration)
    {
        const int g  = lane >> 4;      // row within group-of-4
        const int sl = lane & 15;
        #pragma unroll
        for (int it = 0; it < N_ / (8 * 4); ++it) {   // 8 iterations
            const int n = wave * 32 + it * 4 + g;
            const float* prow = ptile + (size_t)n * D_;
            float p = 0.f;
            #pragma unroll
            for (int c = 0; c < 6; ++c) {
                const int d = c * 64 + 4 * sl;
                float4 a = *reinterpret_cast<const float4*>(prow + d);
                p += a.x * s_qp[d]     + a.y * s_qp[d + 1]
                   + a.z * s_qp[d + 2] + a.w * s_qp[d + 3];
            }
            #pragma unroll
            for (int off = 8; off; off >>= 1)
                p += __shfl_xor(p, off, 16);
            if (sl == 0) s_sc[n] = p;   // TEMP == 1
        }
    }
    __syncthreads();

    // ---- 3. softmax + top-K ----
    // block max
    {
        float v = (tid < N_) ? s_sc[tid] : -INFINITY;
        #pragma unroll
        for (int off = 32; off; off >>= 1) v = fmaxf(v, __shfl_xor(v, off));
        if (lane == 0) s_red[wave] = v;
    }
    __syncthreads();
    float mx = s_red[0];
    #pragma unroll
    for (int i = 1; i < 8; ++i) mx = fmaxf(mx, s_red[i]);

    // rank by comparison count (ranks are a permutation of 0..N_-1 ->
    // exactly K_ selected, jax top_k tie-break by index, deterministic slot)
    float e = 0.f;
    int   cnt = N_;
    if (tid < N_) {
        const float si = s_sc[tid];
        cnt = 0;
        for (int j = 0; j < N_; ++j) {
            const float sj = s_sc[j];
            cnt += (int)(sj > si) | ((int)(sj == si) & (int)(j < tid));
        }
        e = __expf(si - mx);
    }

    // Z = sum all exp, SK = sum of top-K exp
    {
        float z  = e;
        float sk = (cnt < K_) ? e : 0.f;
        #pragma unroll
        for (int off = 32; off; off >>= 1) {
            z  += __shfl_xor(z, off);
            sk += __shfl_xor(sk, off);
        }
        if (lane == 0) { s_red2[wave][0] = z; s_red2[wave][1] = sk; }
    }
    __syncthreads();
    float Z = 0.f, SK = 0.f;
    #pragma unroll
    for (int i = 0; i < 8; ++i) { Z += s_red2[i][0]; SK += s_red2[i][1]; }

    // weight_i = softmax_i / (sum_topk_softmax + EPS) = e_i / (SK + EPS*Z)
    const float inv = 1.f / (SK + 1e-8f * Z);
    if (tid < N_ && cnt < K_) {
        s_ix[cnt] = tid;
        s_w[cnt]  = e * inv;
    }
    __syncthreads();

    // ---- 4. weighted sum over the K selected rows (L2-hot) ----
    for (int d = tid; d < D_; d += NTHREADS) {
        float acc = 0.f;
        #pragma unroll
        for (int j = 0; j < K_; ++j)
            acc += s_w[j] * ptile[(size_t)s_ix[j] * D_ + d];
        s_od[d] = acc;
    }
    __syncthreads();

    // ---- 5. output projection ----
    if (tid < Q_) {
        float acc = b_out[tid];
        #pragma unroll 8
        for (int d = 0; d < D_; ++d)
            acc += s_od[d] * W_out[(size_t)d * Q_ + tid];
        out[(size_t)bt * Q_ + tid] = acc;
    }
}

extern "C" void kernel_launch(void* const* d_in, const int* in_sizes, int n_in,
                              void* d_out, int out_size, void* d_ws, size_t ws_size,
                              hipStream_t stream) {
    const float* queries = (const float*)d_in[0];
    const float* patch   = (const float*)d_in[1];
    const float* W_in    = (const float*)d_in[2];
    const float* b_in    = (const float*)d_in[3];
    const float* W_out   = (const float*)d_in[4];
    const float* b_out   = (const float*)d_in[5];
    float* out = (float*)d_out;

    attn_topk_kernel<<<dim3(BT_), dim3(NTHREADS), 0, stream>>>(
        queries, patch, W_in, b_in, W_out, b_out, out);
}